// Round 5
// baseline (343.733 us; speedup 1.0000x reference)
//
#include <hip/hip_runtime.h>
#include <math.h>

// OverlapTripletLoss: C=64 classes, K=64, ALPHA=1, N=131072, D=256, fp32.
// Pipeline:
//   zeroK/countK/scanK/fillK : group points by label -> idxs[] (group-contiguous)
//   distK : tiled fp32 "GEMM" 64xNxD -> Dg[c][pos] (group-contiguous columns)
//   selK  : per (c,m) pair: exact top-64 mean via binary search on fp32 bit
//           patterns (keys monotone for non-negative floats; ~bits for diag).
//           128 thr/wg + 8.2 KB LDS -> 16 wgs/CU, whole 4096-wg grid resident.
//   lossK : sum over m!=c of max(1 + pos[c] - neg[m][c], 0) / N
// Workspace: needs 557056 + 64*N*4 bytes (~34.1 MB). Guarded against
// undersized ws (writes sentinel instead of corrupting memory).

#define DDIM 256
#define CC 64
#define KSEL 64
#define TPTS 256   // points per workgroup in distK
#define KC 32      // K-chunk (d dimension)
#define XSTR 260   // 256 + 4 pad (keeps 16B alignment for b128 reads)
#define MSTR 68    // 64 + 4 pad
#define SELN 2048  // points per group staged in selK LDS (input has exactly N/CC=2048)

__global__ __launch_bounds__(128) void zeroK(int* cnts) {
  cnts[threadIdx.x] = 0;  // cnt[64] + cnt2[64] contiguous
}

__global__ __launch_bounds__(256) void countK(const int* __restrict__ y, int* cnt, int N) {
  int i = blockIdx.x * 256 + threadIdx.x;
  if (i < N) atomicAdd(&cnt[y[3 * i + 2] & (CC - 1)], 1);
}

__global__ void scanK(const int* __restrict__ cnt, int* base) {
  if (threadIdx.x == 0) {
    int s = 0;
    for (int i = 0; i < CC; ++i) { base[i] = s; s += cnt[i]; }
  }
}

__global__ __launch_bounds__(256) void fillK(const int* __restrict__ y, const int* __restrict__ base,
                                             int* cnt2, int* idxs, int N) {
  int i = blockIdx.x * 256 + threadIdx.x;
  if (i < N) {
    int m = y[3 * i + 2] & (CC - 1);
    int r = atomicAdd(&cnt2[m], 1);      // order within group is irrelevant
    idxs[base[m] + r] = i;
  }
}

// Distance kernel: each wg computes all 64 centroids x 256 (group-sorted) points.
// Thread tile 8c x 8p, K-chunked LDS staging of both operands.
__global__ __launch_bounds__(256) void distK(const float* __restrict__ x, const float* __restrict__ mu,
                                             const int* __restrict__ idxs, float* __restrict__ Dg, int N) {
  __shared__ __align__(16) float xT[KC][XSTR];   // xT[d][p]
  __shared__ __align__(16) float muT[KC][MSTR];  // muT[d][c]
  __shared__ int pid[TPTS];
  __shared__ float xn2[TPTS];
  __shared__ float mun2[CC];
  const int t = threadIdx.x;
  const int wgp0 = blockIdx.x * TPTS;
  pid[t] = idxs[wgp0 + t];

  float acc[8][8];
  #pragma unroll
  for (int a = 0; a < 8; ++a)
    #pragma unroll
    for (int b = 0; b < 8; ++b) acc[a][b] = 0.f;
  float xn2r = 0.f, mun2r = 0.f;

  const int q = t & 7, pr = t >> 3;     // x staging: lane -> (d-quad, point-row)
  const int cs = t >> 2, qs = t & 3;    // mu staging
  const int p0 = (t & 31) * 4;          // thread's points: p0..p0+3 and p0+128..p0+131
  const int c0 = (t >> 5) * 8;          // thread's 8 centroids

  for (int ch = 0; ch < DDIM / KC; ++ch) {
    const int dbase = ch * KC;
    __syncthreads();  // covers pid visibility (iter 0) and xT/muT reuse
    #pragma unroll
    for (int r = 0; r < 8; ++r) {
      const int p = r * 32 + pr;
      const float4 v = *reinterpret_cast<const float4*>(x + (size_t)pid[p] * DDIM + dbase + 4 * q);
      xT[4 * q + 0][p] = v.x; xT[4 * q + 1][p] = v.y;
      xT[4 * q + 2][p] = v.z; xT[4 * q + 3][p] = v.w;
    }
    #pragma unroll
    for (int r = 0; r < 2; ++r) {
      const int q2 = qs + 4 * r;
      const float4 v = *reinterpret_cast<const float4*>(mu + cs * DDIM + dbase + 4 * q2);
      muT[4 * q2 + 0][cs] = v.x; muT[4 * q2 + 1][cs] = v.y;
      muT[4 * q2 + 2][cs] = v.z; muT[4 * q2 + 3][cs] = v.w;
    }
    __syncthreads();
    // squared norms (thread t owns local point t; threads 0..63 own centroids)
    #pragma unroll 8
    for (int dd = 0; dd < KC; ++dd) { const float xv = xT[dd][t]; xn2r = fmaf(xv, xv, xn2r); }
    if (t < CC) {
      #pragma unroll 8
      for (int dd = 0; dd < KC; ++dd) { const float mv = muT[dd][t]; mun2r = fmaf(mv, mv, mun2r); }
    }
    // main FMA loop: 64 FMA per d per thread
    #pragma unroll 4
    for (int dd = 0; dd < KC; ++dd) {
      const float4 xa = *reinterpret_cast<const float4*>(&xT[dd][p0]);
      const float4 xb = *reinterpret_cast<const float4*>(&xT[dd][p0 + 128]);
      const float4 ma = *reinterpret_cast<const float4*>(&muT[dd][c0]);
      const float4 mb = *reinterpret_cast<const float4*>(&muT[dd][c0 + 4]);
      const float xs[8] = {xa.x, xa.y, xa.z, xa.w, xb.x, xb.y, xb.z, xb.w};
      const float ms[8] = {ma.x, ma.y, ma.z, ma.w, mb.x, mb.y, mb.z, mb.w};
      #pragma unroll
      for (int ci = 0; ci < 8; ++ci)
        #pragma unroll
        for (int pj = 0; pj < 8; ++pj)
          acc[ci][pj] = fmaf(ms[ci], xs[pj], acc[ci][pj]);
    }
  }
  xn2[t] = xn2r;
  if (t < CC) mun2[t] = mun2r;
  __syncthreads();

  #pragma unroll
  for (int ci = 0; ci < 8; ++ci) {
    const int c = c0 + ci;
    const float mn = mun2[c];
    #pragma unroll
    for (int h = 0; h < 2; ++h) {
      const int pb = p0 + h * 128;
      float4 o;
      float* op = &o.x;
      #pragma unroll
      for (int j = 0; j < 4; ++j) {
        const float d2 = mn + xn2[pb + j] - 2.f * acc[ci][4 * h + j];
        op[j] = sqrtf(fmaxf(d2, 0.f));
      }
      *reinterpret_cast<float4*>(Dg + (size_t)c * N + wgp0 + pb) = o;  // contiguous, coalesced
    }
  }
}

// Selection: one wg (128 thr) per (c,m). Exact top-64 via bisection on fp32 bit
// space. Distances are >= 0 so bits(v) is order-isomorphic to v; diag uses
// ~bits(v) (order-reversing) so "64 smallest keys" = 64 largest values.
// Exact with ties: sum = sum_{key<kth} val + (KSEL - cnt_less) * val(kth).
// Pads (0xFFFFFFFF) are never counted: mid < hi <= kmax(real) < pad.
__global__ __launch_bounds__(128) void selK(const float* __restrict__ Dg, const int* __restrict__ cnt,
                                            const int* __restrict__ base, float* __restrict__ posM,
                                            float* __restrict__ neg, int N) {
  __shared__ __align__(16) unsigned int keys[SELN];
  __shared__ unsigned int sh_lo, sh_hi;
  __shared__ int sh_cnt[2];
  __shared__ float sh_sum[2];
  const int c = blockIdx.x, m = blockIdx.y;
  const int t = threadIdx.x;
  const int w = t >> 6, lane = t & 63;
  const bool diag = (c == m);
  int cm = cnt[m]; if (cm > SELN) cm = SELN;
  const int bm = base[m];
  const float* src = Dg + (size_t)c * N + bm;
  const int cm4 = (cm + 3) & ~3;

  // load + monotone key transform + min/max (pad to multiple of 4 with max key)
  unsigned int kmin = 0xFFFFFFFFu, kmax = 0u;
  for (int i = t; i < cm4; i += 128) {
    unsigned int key = 0xFFFFFFFFu;
    if (i < cm) {
      const unsigned int b = __float_as_uint(src[i]);
      key = diag ? ~b : b;
      kmin = min(kmin, key); kmax = max(kmax, key);
    }
    keys[i] = key;
  }
  #pragma unroll
  for (int off = 32; off > 0; off >>= 1) {
    kmin = min(kmin, (unsigned int)__shfl_xor((int)kmin, off, 64));
    kmax = max(kmax, (unsigned int)__shfl_xor((int)kmax, off, 64));
  }
  if (lane == 0) { sh_cnt[w] = (int)kmin; sh_sum[w] = __uint_as_float(kmax); }
  __syncthreads();
  if (t == 0) {
    sh_lo = min((unsigned int)sh_cnt[0], (unsigned int)sh_cnt[1]);
    sh_hi = max(__float_as_uint(sh_sum[0]), __float_as_uint(sh_sum[1]));
  }

  // bisection: smallest key T with count(key <= T) >= KSEL  (uniform loop)
  for (;;) {
    __syncthreads();                     // publishes sh_lo/sh_hi from t0
    const unsigned int lo = sh_lo, hi = sh_hi;
    if (lo >= hi) break;
    const unsigned int mid = lo + ((hi - lo) >> 1);
    int cl = 0;
    for (int i4 = t * 4; i4 < cm4; i4 += 512) {
      const uint4 kv = *reinterpret_cast<const uint4*>(&keys[i4]);
      cl += (int)(kv.x <= mid) + (int)(kv.y <= mid) + (int)(kv.z <= mid) + (int)(kv.w <= mid);
    }
    #pragma unroll
    for (int off = 32; off > 0; off >>= 1) cl += __shfl_xor(cl, off, 64);
    if (lane == 0) sh_cnt[w] = cl;
    __syncthreads();
    if (t == 0) {
      if (sh_cnt[0] + sh_cnt[1] >= KSEL) sh_hi = mid; else sh_lo = mid + 1;
    }
  }
  const unsigned int kth = sh_lo;

  // exact sum of top-KSEL with tie handling (pads: key >= kth, never summed)
  int cl = 0; float sl = 0.f;
  for (int i4 = t * 4; i4 < cm4; i4 += 512) {
    const uint4 kv = *reinterpret_cast<const uint4*>(&keys[i4]);
    const unsigned int ks[4] = {kv.x, kv.y, kv.z, kv.w};
    #pragma unroll
    for (int j = 0; j < 4; ++j) {
      if (ks[j] < kth) { ++cl; sl += __uint_as_float(diag ? ~ks[j] : ks[j]); }
    }
  }
  #pragma unroll
  for (int off = 32; off > 0; off >>= 1) {
    cl += __shfl_xor(cl, off, 64);
    sl += __shfl_xor(sl, off, 64);
  }
  if (lane == 0) { sh_cnt[w] = cl; sh_sum[w] = sl; }
  __syncthreads();
  if (t == 0) {
    const int totc = sh_cnt[0] + sh_cnt[1];
    const float tots = sh_sum[0] + sh_sum[1];
    const float kval = __uint_as_float(diag ? ~kth : kth);
    const float mval = (tots + (float)(KSEL - totc) * kval) * (1.0f / KSEL);
    if (diag) posM[c] = mval; else neg[m * CC + c] = mval;
  }
}

__global__ __launch_bounds__(256) void lossK(const float* __restrict__ posM, const float* __restrict__ neg,
                                             float* __restrict__ out, int N) {
  __shared__ float red[256];
  const int t = threadIdx.x;
  float s = 0.f;
  for (int idx = t; idx < CC * CC; idx += 256) {
    const int m = idx >> 6, c = idx & 63;
    if (m != c) {
      const float h = 1.0f + posM[c] - neg[idx];
      s += fmaxf(h, 0.0f);
    }
  }
  red[t] = s;
  __syncthreads();
  for (int off = 128; off > 0; off >>= 1) {
    if (t < off) red[t] += red[t + off];
    __syncthreads();
  }
  if (t == 0) out[0] = red[0] / (float)N;
}

__global__ void wsFailK(float* out) {
  if (threadIdx.x == 0) out[0] = -1.0e30f;  // sentinel: workspace too small
}

extern "C" void kernel_launch(void* const* d_in, const int* in_sizes, int n_in,
                              void* d_out, int out_size, void* d_ws, size_t ws_size,
                              hipStream_t stream) {
  const float* x  = (const float*)d_in[0];
  const int*   y  = (const int*)d_in[1];
  const float* mu = (const float*)d_in[2];
  float* out = (float*)d_out;
  const int N = in_sizes[0] / DDIM;

  // Workspace layout (bytes):
  //   0: cnt[64], 256: cnt2[64], 512: base[64], 768: posM[64], 1024: neg[4096],
  //   32768: idxs[N], 557056: Dg[64*N]  (total ~34.1 MB)
  const size_t need = (size_t)557056 + (size_t)CC * (size_t)N * 4;
  if (ws_size < need) {  // refuse to write OOB; emit sentinel (deterministic)
    hipLaunchKernelGGL(wsFailK, dim3(1), dim3(64), 0, stream, out);
    return;
  }
  char* w = (char*)d_ws;
  int*   cnt  = (int*)(w);
  int*   cnt2 = (int*)(w + 256);
  int*   base = (int*)(w + 512);
  float* posM = (float*)(w + 768);
  float* neg  = (float*)(w + 1024);
  int*   idxs = (int*)(w + 32768);
  float* Dg   = (float*)(w + 557056);

  hipLaunchKernelGGL(zeroK, dim3(1), dim3(128), 0, stream, cnt);
  hipLaunchKernelGGL(countK, dim3((N + 255) / 256), dim3(256), 0, stream, y, cnt, N);
  hipLaunchKernelGGL(scanK, dim3(1), dim3(64), 0, stream, cnt, base);
  hipLaunchKernelGGL(fillK, dim3((N + 255) / 256), dim3(256), 0, stream, y, base, cnt2, idxs, N);
  hipLaunchKernelGGL(distK, dim3(N / TPTS), dim3(256), 0, stream, x, mu, idxs, Dg, N);
  hipLaunchKernelGGL(selK, dim3(CC, CC), dim3(128), 0, stream, Dg, cnt, base, posM, neg, N);
  hipLaunchKernelGGL(lossK, dim3(1), dim3(256), 0, stream, posM, neg, out, N);
}

// Round 7
// 331.648 us; speedup vs baseline: 1.0364x; 1.0364x over previous
//
#include <hip/hip_runtime.h>
#include <math.h>

// OverlapTripletLoss: C=64 classes, K=64, ALPHA=1, N=131072, D=256, fp32.
// Pipeline:
//   zeroK/countK/scanK/fillK : group points by label -> idxs[] (group-contiguous)
//   distK : MFMA bf16x3-split GEMM 64xNxD (hi*hi + hi*lo + lo*hi, fp32 norms)
//           -> Dg[c][pos] (group-contiguous columns). ~2^-17 rel err on d^2.
//   selK  : per (c,m) pair: exact top-64 mean via bisection on fp32 bit keys.
//   lossK : sum over m!=c of max(1 + pos[c] - neg[m][c], 0) / N

#define DDIM 256
#define CC 64
#define KSEL 64
#define TPTS 256   // points per workgroup in distK
#define XS 48      // LDS row stride (shorts): 96B, 16B-aligned rows for b128 reads
#define SELN 2048

typedef short s4v __attribute__((ext_vector_type(4)));
typedef short s8v __attribute__((ext_vector_type(8)));
typedef float f4v __attribute__((ext_vector_type(4)));

__device__ __forceinline__ void cvt_split(float f, short& h, short& l) {
  const unsigned int u = __float_as_uint(f);
  const unsigned int hb = (u + 0x7FFFu + ((u >> 16) & 1u)) >> 16;   // RNE bf16
  h = (short)hb;
  const float rem = f - __uint_as_float(hb << 16);
  const unsigned int ur = __float_as_uint(rem);
  l = (short)((ur + 0x7FFFu + ((ur >> 16) & 1u)) >> 16);
}

__global__ __launch_bounds__(128) void zeroK(int* cnts) {
  cnts[threadIdx.x] = 0;  // cnt[64] + cnt2[64] contiguous
}

__global__ __launch_bounds__(256) void countK(const int* __restrict__ y, int* cnt, int N) {
  int i = blockIdx.x * 256 + threadIdx.x;
  if (i < N) atomicAdd(&cnt[y[3 * i + 2] & (CC - 1)], 1);
}

__global__ void scanK(const int* __restrict__ cnt, int* base) {
  if (threadIdx.x == 0) {
    int s = 0;
    for (int i = 0; i < CC; ++i) { base[i] = s; s += cnt[i]; }
  }
}

__global__ __launch_bounds__(256) void fillK(const int* __restrict__ y, const int* __restrict__ base,
                                             int* cnt2, int* idxs, int N) {
  int i = blockIdx.x * 256 + threadIdx.x;
  if (i < N) {
    int m = y[3 * i + 2] & (CC - 1);
    int r = atomicAdd(&cnt2[m], 1);      // order within group is irrelevant
    idxs[base[m] + r] = i;
  }
}

// MFMA distance kernel. Per wg: 256 group-ordered points x all 64 centroids.
// Wave w owns points [w*64, w*64+64): 4 n-tiles x 4 m-tiles of 16x16, K=256 in
// 8 chunks of 32. A=mu (D rows), B=x[point][k] (D cols); verified gfx950
// mapping: a/b lane l -> (idx=l&15, k=(l>>4)*8+e); D lane l reg r ->
// (row=(l>>4)*4+r, col=l&15).
__global__ __launch_bounds__(256) void distK(const float* __restrict__ x, const float* __restrict__ mu,
                                             const int* __restrict__ idxs, float* __restrict__ Dg, int N) {
  __shared__ __align__(16) short xh[TPTS][XS];
  __shared__ __align__(16) short xl[TPTS][XS];
  __shared__ __align__(16) short mh[CC][XS];
  __shared__ __align__(16) short ml[CC][XS];
  __shared__ int pid[TPTS];
  __shared__ float xn2[TPTS];
  __shared__ float mn2[CC];

  const int t = threadIdx.x;
  const int wgp0 = blockIdx.x * TPTS;
  pid[t] = idxs[wgp0 + t];

  const int q = t & 7,  pr = t >> 3;    // x staging: k-quad, point-row (32/pass)
  const int q2 = t & 3, mm = t >> 2;    // mu staging: k-oct, centroid
  const int w = t >> 6, l = t & 63;     // wave, lane
  const int lr = l & 15, lk = l >> 4;   // frag idx, k-group

  f4v acc[4][4];
  #pragma unroll
  for (int a = 0; a < 4; ++a)
    #pragma unroll
    for (int b = 0; b < 4; ++b) acc[a][b] = (f4v)0.f;
  float xnacc[8] = {0.f, 0.f, 0.f, 0.f, 0.f, 0.f, 0.f, 0.f};
  float mnacc = 0.f;

  __syncthreads();                       // pid visible
  int pidr[8];
  #pragma unroll
  for (int r = 0; r < 8; ++r) pidr[r] = pid[r * 32 + pr];

  for (int ch = 0; ch < 8; ++ch) {
    const int kb = ch * 32;
    if (ch) __syncthreads();             // previous MFMA phase done before overwrite
    // ---- stage x (256 pts x 32 k): fp32 -> bf16 hi/lo, fp32 norm partials ----
    #pragma unroll
    for (int r = 0; r < 8; ++r) {
      const float4 v = *reinterpret_cast<const float4*>(x + (size_t)pidr[r] * DDIM + kb + q * 4);
      const float vs[4] = {v.x, v.y, v.z, v.w};
      s4v hv, lv;
      float s2 = 0.f;
      #pragma unroll
      for (int j = 0; j < 4; ++j) {
        short hj, lj; cvt_split(vs[j], hj, lj);
        hv[j] = hj; lv[j] = lj;
        s2 = fmaf(vs[j], vs[j], s2);
      }
      xnacc[r] += s2;
      const int p = r * 32 + pr;
      *reinterpret_cast<s4v*>(&xh[p][q * 4]) = hv;
      *reinterpret_cast<s4v*>(&xl[p][q * 4]) = lv;
    }
    // ---- stage mu (64 c x 32 k) ----
    {
      const float* msrc = mu + (size_t)mm * DDIM + kb + q2 * 8;
      const float4 va = *reinterpret_cast<const float4*>(msrc);
      const float4 vb = *reinterpret_cast<const float4*>(msrc + 4);
      const float vs[8] = {va.x, va.y, va.z, va.w, vb.x, vb.y, vb.z, vb.w};
      s4v h0, h1, l0, l1;
      #pragma unroll
      for (int j = 0; j < 4; ++j) {
        short hj, lj; cvt_split(vs[j], hj, lj);
        h0[j] = hj; l0[j] = lj;
        mnacc = fmaf(vs[j], vs[j], mnacc);
      }
      #pragma unroll
      for (int j = 0; j < 4; ++j) {
        short hj, lj; cvt_split(vs[4 + j], hj, lj);
        h1[j] = hj; l1[j] = lj;
        mnacc = fmaf(vs[4 + j], vs[4 + j], mnacc);
      }
      *reinterpret_cast<s4v*>(&mh[mm][q2 * 8])     = h0;
      *reinterpret_cast<s4v*>(&mh[mm][q2 * 8 + 4]) = h1;
      *reinterpret_cast<s4v*>(&ml[mm][q2 * 8])     = l0;
      *reinterpret_cast<s4v*>(&ml[mm][q2 * 8 + 4]) = l1;
    }
    __syncthreads();
    // ---- MFMA phase: 4 m-tiles x 4 n-tiles x 3 split terms ----
    s8v ah[4], al_[4];
    #pragma unroll
    for (int mt = 0; mt < 4; ++mt) {
      ah[mt]  = *reinterpret_cast<const s8v*>(&mh[mt * 16 + lr][lk * 8]);
      al_[mt] = *reinterpret_cast<const s8v*>(&ml[mt * 16 + lr][lk * 8]);
    }
    #pragma unroll
    for (int nt = 0; nt < 4; ++nt) {
      const int prow = w * 64 + nt * 16 + lr;
      const s8v bh = *reinterpret_cast<const s8v*>(&xh[prow][lk * 8]);
      const s8v bl = *reinterpret_cast<const s8v*>(&xl[prow][lk * 8]);
      #pragma unroll
      for (int mt = 0; mt < 4; ++mt) {
        acc[mt][nt] = __builtin_amdgcn_mfma_f32_16x16x32_bf16(ah[mt],  bh, acc[mt][nt], 0, 0, 0);
        acc[mt][nt] = __builtin_amdgcn_mfma_f32_16x16x32_bf16(ah[mt],  bl, acc[mt][nt], 0, 0, 0);
        acc[mt][nt] = __builtin_amdgcn_mfma_f32_16x16x32_bf16(al_[mt], bh, acc[mt][nt], 0, 0, 0);
      }
    }
  }
  // ---- norms: reduce partials across the k-lanes, write to LDS ----
  #pragma unroll
  for (int r = 0; r < 8; ++r) {
    float s = xnacc[r];
    s += __shfl_xor(s, 1, 64); s += __shfl_xor(s, 2, 64); s += __shfl_xor(s, 4, 64);
    if (q == 0) xn2[r * 32 + pr] = s;
  }
  {
    float s = mnacc;
    s += __shfl_xor(s, 1, 64); s += __shfl_xor(s, 2, 64);
    if (q2 == 0) mn2[mm] = s;
  }
  __syncthreads();
  // ---- epilogue: d = sqrt(max(|mu|^2 + |x|^2 - 2*dot, 0)), coalesced 64B rows ----
  #pragma unroll
  for (int mt = 0; mt < 4; ++mt) {
    #pragma unroll
    for (int r = 0; r < 4; ++r) {
      const int m = mt * 16 + lk * 4 + r;
      const float mn = mn2[m];
      #pragma unroll
      for (int nt = 0; nt < 4; ++nt) {
        const int p = w * 64 + nt * 16 + lr;
        const float d2 = mn + xn2[p] - 2.f * acc[mt][nt][r];
        Dg[(size_t)m * N + wgp0 + p] = sqrtf(fmaxf(d2, 0.f));
      }
    }
  }
}

// Selection: one wg (128 thr) per (c,m). Exact top-64 via bisection on fp32 bit
// space. Distances are >= 0 so bits(v) is order-isomorphic to v; diag uses
// ~bits(v) (order-reversing) so "64 smallest keys" = 64 largest values.
// Exact with ties: sum = sum_{key<kth} val + (KSEL - cnt_less) * val(kth).
__global__ __launch_bounds__(128) void selK(const float* __restrict__ Dg, const int* __restrict__ cnt,
                                            const int* __restrict__ base, float* __restrict__ posM,
                                            float* __restrict__ neg, int N) {
  __shared__ __align__(16) unsigned int keys[SELN];
  __shared__ unsigned int sh_lo, sh_hi;
  __shared__ int sh_cnt[2];
  __shared__ float sh_sum[2];
  const int c = blockIdx.x, m = blockIdx.y;
  const int t = threadIdx.x;
  const int w = t >> 6, lane = t & 63;
  const bool diag = (c == m);
  int cm = cnt[m]; if (cm > SELN) cm = SELN;
  const int bm = base[m];
  const float* src = Dg + (size_t)c * N + bm;
  const int cm4 = (cm + 3) & ~3;

  unsigned int kmin = 0xFFFFFFFFu, kmax = 0u;
  for (int i = t; i < cm4; i += 128) {
    unsigned int key = 0xFFFFFFFFu;
    if (i < cm) {
      const unsigned int b = __float_as_uint(src[i]);
      key = diag ? ~b : b;
      kmin = min(kmin, key); kmax = max(kmax, key);
    }
    keys[i] = key;
  }
  #pragma unroll
  for (int off = 32; off > 0; off >>= 1) {
    kmin = min(kmin, (unsigned int)__shfl_xor((int)kmin, off, 64));
    kmax = max(kmax, (unsigned int)__shfl_xor((int)kmax, off, 64));
  }
  if (lane == 0) { sh_cnt[w] = (int)kmin; sh_sum[w] = __uint_as_float(kmax); }
  __syncthreads();
  if (t == 0) {
    sh_lo = min((unsigned int)sh_cnt[0], (unsigned int)sh_cnt[1]);
    sh_hi = max(__float_as_uint(sh_sum[0]), __float_as_uint(sh_sum[1]));
  }

  for (;;) {
    __syncthreads();
    const unsigned int lo = sh_lo, hi = sh_hi;
    if (lo >= hi) break;
    const unsigned int mid = lo + ((hi - lo) >> 1);
    int cl = 0;
    for (int i4 = t * 4; i4 < cm4; i4 += 512) {
      const uint4 kv = *reinterpret_cast<const uint4*>(&keys[i4]);
      cl += (int)(kv.x <= mid) + (int)(kv.y <= mid) + (int)(kv.z <= mid) + (int)(kv.w <= mid);
    }
    #pragma unroll
    for (int off = 32; off > 0; off >>= 1) cl += __shfl_xor(cl, off, 64);
    if (lane == 0) sh_cnt[w] = cl;
    __syncthreads();
    if (t == 0) {
      if (sh_cnt[0] + sh_cnt[1] >= KSEL) sh_hi = mid; else sh_lo = mid + 1;
    }
  }
  const unsigned int kth = sh_lo;

  int cl = 0; float sl = 0.f;
  for (int i4 = t * 4; i4 < cm4; i4 += 512) {
    const uint4 kv = *reinterpret_cast<const uint4*>(&keys[i4]);
    const unsigned int ks[4] = {kv.x, kv.y, kv.z, kv.w};
    #pragma unroll
    for (int j = 0; j < 4; ++j) {
      if (ks[j] < kth) { ++cl; sl += __uint_as_float(diag ? ~ks[j] : ks[j]); }
    }
  }
  #pragma unroll
  for (int off = 32; off > 0; off >>= 1) {
    cl += __shfl_xor(cl, off, 64);
    sl += __shfl_xor(sl, off, 64);
  }
  if (lane == 0) { sh_cnt[w] = cl; sh_sum[w] = sl; }
  __syncthreads();
  if (t == 0) {
    const int totc = sh_cnt[0] + sh_cnt[1];
    const float tots = sh_sum[0] + sh_sum[1];
    const float kval = __uint_as_float(diag ? ~kth : kth);
    const float mval = (tots + (float)(KSEL - totc) * kval) * (1.0f / KSEL);
    if (diag) posM[c] = mval; else neg[m * CC + c] = mval;
  }
}

__global__ __launch_bounds__(256) void lossK(const float* __restrict__ posM, const float* __restrict__ neg,
                                             float* __restrict__ out, int N) {
  __shared__ float red[256];
  const int t = threadIdx.x;
  float s = 0.f;
  for (int idx = t; idx < CC * CC; idx += 256) {
    const int m = idx >> 6, c = idx & 63;
    if (m != c) {
      const float h = 1.0f + posM[c] - neg[idx];
      s += fmaxf(h, 0.0f);
    }
  }
  red[t] = s;
  __syncthreads();
  for (int off = 128; off > 0; off >>= 1) {
    if (t < off) red[t] += red[t + off];
    __syncthreads();
  }
  if (t == 0) out[0] = red[0] / (float)N;
}

__global__ void wsFailK(float* out) {
  if (threadIdx.x == 0) out[0] = -1.0e30f;  // sentinel: workspace too small
}

extern "C" void kernel_launch(void* const* d_in, const int* in_sizes, int n_in,
                              void* d_out, int out_size, void* d_ws, size_t ws_size,
                              hipStream_t stream) {
  const float* x  = (const float*)d_in[0];
  const int*   y  = (const int*)d_in[1];
  const float* mu = (const float*)d_in[2];
  float* out = (float*)d_out;
  const int N = in_sizes[0] / DDIM;

  // Workspace layout (bytes):
  //   0: cnt[64], 256: cnt2[64], 512: base[64], 768: posM[64], 1024: neg[4096],
  //   32768: idxs[N], 557056: Dg[64*N]  (total ~34.1 MB)
  const size_t need = (size_t)557056 + (size_t)CC * (size_t)N * 4;
  if (ws_size < need) {  // refuse to write OOB; emit sentinel (deterministic)
    hipLaunchKernelGGL(wsFailK, dim3(1), dim3(64), 0, stream, out);
    return;
  }
  char* w = (char*)d_ws;
  int*   cnt  = (int*)(w);
  int*   cnt2 = (int*)(w + 256);
  int*   base = (int*)(w + 512);
  float* posM = (float*)(w + 768);
  float* neg  = (float*)(w + 1024);
  int*   idxs = (int*)(w + 32768);
  float* Dg   = (float*)(w + 557056);

  hipLaunchKernelGGL(zeroK, dim3(1), dim3(128), 0, stream, cnt);
  hipLaunchKernelGGL(countK, dim3((N + 255) / 256), dim3(256), 0, stream, y, cnt, N);
  hipLaunchKernelGGL(scanK, dim3(1), dim3(64), 0, stream, cnt, base);
  hipLaunchKernelGGL(fillK, dim3((N + 255) / 256), dim3(256), 0, stream, y, base, cnt2, idxs, N);
  hipLaunchKernelGGL(distK, dim3(N / TPTS), dim3(256), 0, stream, x, mu, idxs, Dg, N);
  hipLaunchKernelGGL(selK, dim3(CC, CC), dim3(128), 0, stream, Dg, cnt, base, posM, neg, N);
  hipLaunchKernelGGL(lossK, dim3(1), dim3(256), 0, stream, posM, neg, out, N);
}

// Round 8
// 331.308 us; speedup vs baseline: 1.0375x; 1.0010x over previous
//
#include <hip/hip_runtime.h>
#include <math.h>

// OverlapTripletLoss: C=64 classes, K=64, ALPHA=1, N=131072, D=256, fp32.
// Pipeline:
//   prepK  : zero counters + convert mu -> bf16 hi/lo (global, L2-hot) + mu norms
//   countK/scanK/fillK : group points by label -> idxs[] (group-contiguous)
//   distK  : MFMA bf16x3-split GEMM (hi*hi + hi*lo + lo*hi, fp32 norms).
//            128 pts/wg, 21 KB LDS -> 4 wgs/CU, async prefetch of x + mu frags.
//   selK   : per (c,m) pair: exact top-64 mean via bisection on fp32 bit keys.
//   lossK  : sum over m!=c of max(1 + pos[c] - neg[m][c], 0) / N

#define DDIM 256
#define CC 64
#define KSEL 64
#define TPTS 128   // points per workgroup in distK
#define XS 40      // LDS row stride (shorts): 80B -> 16B-aligned rows, 8-bank spread
#define SELN 2048

typedef short s4v __attribute__((ext_vector_type(4)));
typedef short s8v __attribute__((ext_vector_type(8)));
typedef float f4v __attribute__((ext_vector_type(4)));

__device__ __forceinline__ void cvt_split(float f, short& h, short& l) {
  const unsigned int u = __float_as_uint(f);
  const unsigned int hb = (u + 0x7FFFu + ((u >> 16) & 1u)) >> 16;   // RNE bf16
  h = (short)hb;
  const float rem = f - __uint_as_float(hb << 16);
  const unsigned int ur = __float_as_uint(rem);
  l = (short)((ur + 0x7FFFu + ((ur >> 16) & 1u)) >> 16);
}

// prepK: wg0 zeroes cnt/cnt2; all 16 wgs convert mu (64x256) to bf16 hi/lo and
// compute row norms. Row = b*4 + (t>>6); lane handles 4 consecutive values.
__global__ __launch_bounds__(256) void prepK(const float* __restrict__ mu, short* __restrict__ mhG,
                                             short* __restrict__ mlG, float* __restrict__ mn2G,
                                             int* __restrict__ cnts) {
  const int b = blockIdx.x, t = threadIdx.x;
  if (b == 0 && t < 128) cnts[t] = 0;
  const int row = b * 4 + (t >> 6), l = t & 63;
  const float4 v = *reinterpret_cast<const float4*>(mu + (size_t)row * DDIM + l * 4);
  const float vs[4] = {v.x, v.y, v.z, v.w};
  s4v hv, lv;
  float s2 = 0.f;
  #pragma unroll
  for (int j = 0; j < 4; ++j) {
    short hj, lj; cvt_split(vs[j], hj, lj);
    hv[j] = hj; lv[j] = lj;
    s2 = fmaf(vs[j], vs[j], s2);
  }
  *reinterpret_cast<s4v*>(&mhG[(size_t)row * DDIM + l * 4]) = hv;
  *reinterpret_cast<s4v*>(&mlG[(size_t)row * DDIM + l * 4]) = lv;
  #pragma unroll
  for (int off = 32; off > 0; off >>= 1) s2 += __shfl_xor(s2, off, 64);
  if (l == 0) mn2G[row] = s2;
}

__global__ __launch_bounds__(256) void countK(const int* __restrict__ y, int* cnt, int N) {
  int i = blockIdx.x * 256 + threadIdx.x;
  if (i < N) atomicAdd(&cnt[y[3 * i + 2] & (CC - 1)], 1);
}

__global__ void scanK(const int* __restrict__ cnt, int* base) {
  if (threadIdx.x == 0) {
    int s = 0;
    for (int i = 0; i < CC; ++i) { base[i] = s; s += cnt[i]; }
  }
}

__global__ __launch_bounds__(256) void fillK(const int* __restrict__ y, const int* __restrict__ base,
                                             int* cnt2, int* idxs, int N) {
  int i = blockIdx.x * 256 + threadIdx.x;
  if (i < N) {
    int m = y[3 * i + 2] & (CC - 1);
    int r = atomicAdd(&cnt2[m], 1);      // order within group is irrelevant
    idxs[base[m] + r] = i;
  }
}

// MFMA distance kernel v2. Per wg: 128 group-ordered points x all 64 centroids.
// 4 waves; wave w owns 32 points (2 n-tiles) x 64 centroids (4 m-tiles),
// K=256 in 8 chunks of 32. A=mu frags straight from global (mhG/mlG, L2-hot);
// B=x staged in LDS as bf16 hi/lo. Async: A-loads issued before cvt phase,
// next x-chunk loads issued before MFMA phase.
// Verified gfx950 16x16x32 mapping: a/b lane l -> (idx=l&15, k=(l>>4)*8+e);
// D lane l reg r -> (row=(l>>4)*4+r, col=l&15).
__global__ __launch_bounds__(256, 4) void distK(const float* __restrict__ x, const short* __restrict__ mhG,
                                                const short* __restrict__ mlG, const float* __restrict__ mn2G,
                                                const int* __restrict__ idxs, float* __restrict__ Dg, int N) {
  __shared__ __align__(16) short xh[TPTS][XS];
  __shared__ __align__(16) short xl[TPTS][XS];
  __shared__ int pid[TPTS];
  __shared__ float xn2[TPTS];

  const int t = threadIdx.x;
  const int wgp0 = blockIdx.x * TPTS;
  if (t < TPTS) pid[t] = idxs[wgp0 + t];

  const int q = t & 7, pr = t >> 3;     // staging: k-quad, point-row (32 rows/pass)
  const int w = t >> 6, l = t & 63;     // wave, lane
  const int lr = l & 15, lk = l >> 4;   // frag idx, k-group

  f4v acc[4][2];                        // [m-tile][n-tile]
  #pragma unroll
  for (int a = 0; a < 4; ++a)
    #pragma unroll
    for (int b = 0; b < 2; ++b) acc[a][b] = (f4v)0.f;
  float xnacc[4] = {0.f, 0.f, 0.f, 0.f};

  __syncthreads();                      // pid visible
  int pidr[4];
  #pragma unroll
  for (int p = 0; p < 4; ++p) pidr[p] = pid[p * 32 + pr];

  // prologue: chunk-0 x loads in flight
  float4 vreg[4];
  #pragma unroll
  for (int p = 0; p < 4; ++p)
    vreg[p] = *reinterpret_cast<const float4*>(x + (size_t)pidr[p] * DDIM + q * 4);

  for (int ch = 0; ch < 8; ++ch) {
    const int kb = ch * 32;
    // ---- issue A-frag loads early (global, L2-hot; latency hides under cvt) ----
    s8v ah[4], al_[4];
    #pragma unroll
    for (int mt = 0; mt < 4; ++mt) {
      const size_t ro = (size_t)(mt * 16 + lr) * DDIM + kb + lk * 8;
      ah[mt]  = *reinterpret_cast<const s8v*>(mhG + ro);
      al_[mt] = *reinterpret_cast<const s8v*>(mlG + ro);
    }
    // ---- cvt + store x chunk (consumes vreg) ----
    #pragma unroll
    for (int p = 0; p < 4; ++p) {
      const float vs[4] = {vreg[p].x, vreg[p].y, vreg[p].z, vreg[p].w};
      s4v hv, lv;
      float s2 = 0.f;
      #pragma unroll
      for (int j = 0; j < 4; ++j) {
        short hj, lj; cvt_split(vs[j], hj, lj);
        hv[j] = hj; lv[j] = lj;
        s2 = fmaf(vs[j], vs[j], s2);
      }
      xnacc[p] += s2;
      const int pt = p * 32 + pr;
      *reinterpret_cast<s4v*>(&xh[pt][q * 4]) = hv;
      *reinterpret_cast<s4v*>(&xl[pt][q * 4]) = lv;
    }
    __syncthreads();                    // x stores visible
    // ---- prefetch next x chunk (overlaps MFMA) ----
    if (ch < 7) {
      #pragma unroll
      for (int p = 0; p < 4; ++p)
        vreg[p] = *reinterpret_cast<const float4*>(x + (size_t)pidr[p] * DDIM + kb + 32 + q * 4);
    }
    // ---- B frags from LDS ----
    s8v bh[2], bl[2];
    #pragma unroll
    for (int nt = 0; nt < 2; ++nt) {
      const int prow = w * 32 + nt * 16 + lr;
      bh[nt] = *reinterpret_cast<const s8v*>(&xh[prow][lk * 8]);
      bl[nt] = *reinterpret_cast<const s8v*>(&xl[prow][lk * 8]);
    }
    // ---- 24 MFMAs ----
    #pragma unroll
    for (int mt = 0; mt < 4; ++mt) {
      #pragma unroll
      for (int nt = 0; nt < 2; ++nt) {
        acc[mt][nt] = __builtin_amdgcn_mfma_f32_16x16x32_bf16(ah[mt],  bh[nt], acc[mt][nt], 0, 0, 0);
        acc[mt][nt] = __builtin_amdgcn_mfma_f32_16x16x32_bf16(ah[mt],  bl[nt], acc[mt][nt], 0, 0, 0);
        acc[mt][nt] = __builtin_amdgcn_mfma_f32_16x16x32_bf16(al_[mt], bh[nt], acc[mt][nt], 0, 0, 0);
      }
    }
    __syncthreads();                    // LDS consumed before next store
  }
  // ---- x norms: reduce over the 8 q-lanes ----
  #pragma unroll
  for (int p = 0; p < 4; ++p) {
    float s = xnacc[p];
    s += __shfl_xor(s, 1, 64); s += __shfl_xor(s, 2, 64); s += __shfl_xor(s, 4, 64);
    if (q == 0) xn2[p * 32 + pr] = s;
  }
  __syncthreads();
  // ---- epilogue ----
  #pragma unroll
  for (int mt = 0; mt < 4; ++mt) {
    #pragma unroll
    for (int r = 0; r < 4; ++r) {
      const int m = mt * 16 + lk * 4 + r;
      const float mn = mn2G[m];
      #pragma unroll
      for (int nt = 0; nt < 2; ++nt) {
        const int p = w * 32 + nt * 16 + lr;
        const float d2 = mn + xn2[p] - 2.f * acc[mt][nt][r];
        Dg[(size_t)m * N + wgp0 + p] = sqrtf(fmaxf(d2, 0.f));
      }
    }
  }
}

// Selection: one wg (128 thr) per (c,m). Exact top-64 via bisection on fp32 bit
// space. Distances are >= 0 so bits(v) is order-isomorphic to v; diag uses
// ~bits(v) (order-reversing) so "64 smallest keys" = 64 largest values.
// Exact with ties: sum = sum_{key<kth} val + (KSEL - cnt_less) * val(kth).
__global__ __launch_bounds__(128) void selK(const float* __restrict__ Dg, const int* __restrict__ cnt,
                                            const int* __restrict__ base, float* __restrict__ posM,
                                            float* __restrict__ neg, int N) {
  __shared__ __align__(16) unsigned int keys[SELN];
  __shared__ unsigned int sh_lo, sh_hi;
  __shared__ int sh_cnt[2];
  __shared__ float sh_sum[2];
  const int c = blockIdx.x, m = blockIdx.y;
  const int t = threadIdx.x;
  const int w = t >> 6, lane = t & 63;
  const bool diag = (c == m);
  int cm = cnt[m]; if (cm > SELN) cm = SELN;
  const int bm = base[m];
  const float* src = Dg + (size_t)c * N + bm;
  const int cm4 = (cm + 3) & ~3;

  unsigned int kmin = 0xFFFFFFFFu, kmax = 0u;
  for (int i = t; i < cm4; i += 128) {
    unsigned int key = 0xFFFFFFFFu;
    if (i < cm) {
      const unsigned int b = __float_as_uint(src[i]);
      key = diag ? ~b : b;
      kmin = min(kmin, key); kmax = max(kmax, key);
    }
    keys[i] = key;
  }
  #pragma unroll
  for (int off = 32; off > 0; off >>= 1) {
    kmin = min(kmin, (unsigned int)__shfl_xor((int)kmin, off, 64));
    kmax = max(kmax, (unsigned int)__shfl_xor((int)kmax, off, 64));
  }
  if (lane == 0) { sh_cnt[w] = (int)kmin; sh_sum[w] = __uint_as_float(kmax); }
  __syncthreads();
  if (t == 0) {
    sh_lo = min((unsigned int)sh_cnt[0], (unsigned int)sh_cnt[1]);
    sh_hi = max(__float_as_uint(sh_sum[0]), __float_as_uint(sh_sum[1]));
  }

  for (;;) {
    __syncthreads();
    const unsigned int lo = sh_lo, hi = sh_hi;
    if (lo >= hi) break;
    const unsigned int mid = lo + ((hi - lo) >> 1);
    int cl = 0;
    for (int i4 = t * 4; i4 < cm4; i4 += 512) {
      const uint4 kv = *reinterpret_cast<const uint4*>(&keys[i4]);
      cl += (int)(kv.x <= mid) + (int)(kv.y <= mid) + (int)(kv.z <= mid) + (int)(kv.w <= mid);
    }
    #pragma unroll
    for (int off = 32; off > 0; off >>= 1) cl += __shfl_xor(cl, off, 64);
    if (lane == 0) sh_cnt[w] = cl;
    __syncthreads();
    if (t == 0) {
      if (sh_cnt[0] + sh_cnt[1] >= KSEL) sh_hi = mid; else sh_lo = mid + 1;
    }
  }
  const unsigned int kth = sh_lo;

  int cl = 0; float sl = 0.f;
  for (int i4 = t * 4; i4 < cm4; i4 += 512) {
    const uint4 kv = *reinterpret_cast<const uint4*>(&keys[i4]);
    const unsigned int ks[4] = {kv.x, kv.y, kv.z, kv.w};
    #pragma unroll
    for (int j = 0; j < 4; ++j) {
      if (ks[j] < kth) { ++cl; sl += __uint_as_float(diag ? ~ks[j] : ks[j]); }
    }
  }
  #pragma unroll
  for (int off = 32; off > 0; off >>= 1) {
    cl += __shfl_xor(cl, off, 64);
    sl += __shfl_xor(sl, off, 64);
  }
  if (lane == 0) { sh_cnt[w] = cl; sh_sum[w] = sl; }
  __syncthreads();
  if (t == 0) {
    const int totc = sh_cnt[0] + sh_cnt[1];
    const float tots = sh_sum[0] + sh_sum[1];
    const float kval = __uint_as_float(diag ? ~kth : kth);
    const float mval = (tots + (float)(KSEL - totc) * kval) * (1.0f / KSEL);
    if (diag) posM[c] = mval; else neg[m * CC + c] = mval;
  }
}

__global__ __launch_bounds__(256) void lossK(const float* __restrict__ posM, const float* __restrict__ neg,
                                             float* __restrict__ out, int N) {
  __shared__ float red[256];
  const int t = threadIdx.x;
  float s = 0.f;
  for (int idx = t; idx < CC * CC; idx += 256) {
    const int m = idx >> 6, c = idx & 63;
    if (m != c) {
      const float h = 1.0f + posM[c] - neg[idx];
      s += fmaxf(h, 0.0f);
    }
  }
  red[t] = s;
  __syncthreads();
  for (int off = 128; off > 0; off >>= 1) {
    if (t < off) red[t] += red[t + off];
    __syncthreads();
  }
  if (t == 0) out[0] = red[0] / (float)N;
}

__global__ void wsFailK(float* out) {
  if (threadIdx.x == 0) out[0] = -1.0e30f;  // sentinel: workspace too small
}

extern "C" void kernel_launch(void* const* d_in, const int* in_sizes, int n_in,
                              void* d_out, int out_size, void* d_ws, size_t ws_size,
                              hipStream_t stream) {
  const float* x  = (const float*)d_in[0];
  const int*   y  = (const int*)d_in[1];
  const float* mu = (const float*)d_in[2];
  float* out = (float*)d_out;
  const int N = in_sizes[0] / DDIM;

  // Workspace layout (bytes):
  //   0: cnt[64], 256: cnt2[64], 512: base[64], 768: posM[64],
  //   1024: neg[4096] (16 KB), 17408: mn2G[64], 20480: mhG[64*256] bf16 (32 KB),
  //   53248: mlG (32 KB), 131072: idxs[N] (512 KB), 655360: Dg[64*N] (32 MB)
  const size_t need = (size_t)655360 + (size_t)CC * (size_t)N * 4;
  if (ws_size < need) {  // refuse to write OOB; emit sentinel (deterministic)
    hipLaunchKernelGGL(wsFailK, dim3(1), dim3(64), 0, stream, out);
    return;
  }
  char* w = (char*)d_ws;
  int*   cnt  = (int*)(w);
  int*   cnt2 = (int*)(w + 256);
  int*   base = (int*)(w + 512);
  float* posM = (float*)(w + 768);
  float* neg  = (float*)(w + 1024);
  float* mn2G = (float*)(w + 17408);
  short* mhG  = (short*)(w + 20480);
  short* mlG  = (short*)(w + 53248);
  int*   idxs = (int*)(w + 131072);
  float* Dg   = (float*)(w + 655360);

  hipLaunchKernelGGL(prepK, dim3(16), dim3(256), 0, stream, mu, mhG, mlG, mn2G, cnt);
  hipLaunchKernelGGL(countK, dim3((N + 255) / 256), dim3(256), 0, stream, y, cnt, N);
  hipLaunchKernelGGL(scanK, dim3(1), dim3(64), 0, stream, cnt, base);
  hipLaunchKernelGGL(fillK, dim3((N + 255) / 256), dim3(256), 0, stream, y, base, cnt2, idxs, N);
  hipLaunchKernelGGL(distK, dim3(N / TPTS), dim3(256), 0, stream, x, mhG, mlG, mn2G, idxs, Dg, N);
  hipLaunchKernelGGL(selK, dim3(CC, CC), dim3(128), 0, stream, Dg, cnt, base, posM, neg, N);
  hipLaunchKernelGGL(lossK, dim3(1), dim3(256), 0, stream, posM, neg, out, N);
}